// Round 1
// baseline (588.808 us; speedup 1.0000x reference)
//
#include <hip/hip_runtime.h>

#define BB 4
#define NN 8192
#define MM 2048
#define CC 64
#define OPC 64
#define OUTC 256
#define K0 32
#define K1 64

// ---------------------------------------------------------------------------
// Kernel 1: one wave (64 threads) per center.
//   Phase A: scan distance row in 64-chunks, ballot-compact first K0/K1
//            passing indices (== k smallest indices, matching ref's sort).
//            Early exit when both rings full (~4-6 chunks for uniform data).
//   Phase B: per ring, lane = neighbor slot. x[67] (rel+feat) in VGPRs,
//            W rows are wave-uniform -> s_load; h[64] accumulators in VGPRs.
//            relu+mask, LDS transpose, lane j maxes column j -> f[j].
//   Writes x_ws[bm][0:64]=f_ring0, [64:128]=f_ring1.
// ---------------------------------------------------------------------------
__global__ __launch_bounds__(64, 2) void op_kernel(
    const float* __restrict__ positions, const float* __restrict__ features,
    const float* __restrict__ centers,   const float* __restrict__ distances,
    const float* __restrict__ W0, const float* __restrict__ b0,
    const float* __restrict__ W1, const float* __restrict__ b1,
    float* __restrict__ xout)
{
    __shared__ int   s_idx0[K0];
    __shared__ int   s_idx1[K1];
    __shared__ float s_h[64][65];   // +1 pad: conflict-free transpose

    const int bm   = blockIdx.x;
    const int b    = bm / MM;
    const int lane = threadIdx.x;

    // ---------------- Phase A: selection ----------------
    const float* drow = distances + (size_t)bm * NN;
    int cnt0 = 0, cnt1 = 0;
    for (int base = 0; base < NN; base += 64) {
        if (cnt0 >= K0 && cnt1 >= K1) break;
        float d = drow[base + lane];
        bool p0 = (d >= 1.0f)  && (d < 2.25f);   // ring0: [min^2=1, 1.5^2)
        bool p1 = (d >= 2.25f) && (d < 9.0f);    // ring1: [1.5^2, 3^2)
        unsigned long long m0 = __ballot(p0);
        unsigned long long m1 = __ballot(p1);
        unsigned long long lt = (1ull << lane) - 1ull;  // lanes below me
        if (cnt0 < K0) {
            int pos = cnt0 + __popcll(m0 & lt);
            if (p0 && pos < K0) s_idx0[pos] = base + lane;
            cnt0 += __popcll(m0);
        }
        if (cnt1 < K1) {
            int pos = cnt1 + __popcll(m1 & lt);
            if (p1 && pos < K1) s_idx1[pos] = base + lane;
            cnt1 += __popcll(m1);
        }
    }
    cnt0 = min(cnt0, K0);
    cnt1 = min(cnt1, K1);
    __syncthreads();

    // center coords (wave-uniform scalar loads)
    const float cx = centers[(size_t)bm * 3 + 0];
    const float cy = centers[(size_t)bm * 3 + 1];
    const float cz = centers[(size_t)bm * 3 + 2];

    // ---------------- Phase B: per-ring op ----------------
    #pragma unroll 1   // share the big unrolled body between rings (I$)
    for (int ring = 0; ring < 2; ++ring) {
        const int    k    = ring ? K1 : K0;
        const int    cnt  = ring ? cnt1 : cnt0;
        const int*   sidx = ring ? s_idx1 : s_idx0;
        const float* W    = ring ? W1 : W0;
        const float* bias = ring ? b1 : b0;

        const bool valid = (lane < k) && (lane < cnt);
        const int  n     = valid ? sidx[lane & (k - 1)] : 0;

        // per-lane input vector: rel(3) + feat(64) in VGPRs
        const float* pp = positions + (size_t)((size_t)b * NN + n) * 3;
        const float rx = pp[0] - cx, ry = pp[1] - cy, rz = pp[2] - cz;

        const float* fp = features + (size_t)((size_t)b * NN + n) * CC;
        float xr[CC];
        #pragma unroll
        for (int q = 0; q < CC / 4; ++q) {
            float4 v = ((const float4*)fp)[q];
            xr[4*q+0] = v.x; xr[4*q+1] = v.y; xr[4*q+2] = v.z; xr[4*q+3] = v.w;
        }

        float h[OPC];
        #pragma unroll
        for (int j = 0; j < OPC; ++j) h[j] = bias[j];          // s_load
        #pragma unroll
        for (int j = 0; j < OPC; ++j) h[j] = fmaf(rx, W[0*OPC + j], h[j]);
        #pragma unroll
        for (int j = 0; j < OPC; ++j) h[j] = fmaf(ry, W[1*OPC + j], h[j]);
        #pragma unroll
        for (int j = 0; j < OPC; ++j) h[j] = fmaf(rz, W[2*OPC + j], h[j]);
        #pragma unroll
        for (int c = 0; c < CC; ++c) {
            const float xc = xr[c];
            const float* Wr = W + (size_t)(3 + c) * OPC;        // wave-uniform
            #pragma unroll
            for (int j = 0; j < OPC; ++j) h[j] = fmaf(xc, Wr[j], h[j]);
        }

        // relu + mask invalid rows, transpose through LDS, max over neighbors
        __syncthreads();
        #pragma unroll
        for (int j = 0; j < OPC; ++j)
            s_h[lane][j] = valid ? fmaxf(h[j], 0.0f) : 0.0f;
        __syncthreads();
        float fm = 0.0f;
        #pragma unroll
        for (int i = 0; i < 64; ++i) fm = fmaxf(fm, s_h[i][lane]);

        xout[(size_t)bm * (2 * OPC) + ring * OPC + lane] = fm;
    }
}

// ---------------------------------------------------------------------------
// Kernel 2: agg conv  out[bm][j2] = relu(x[bm] . W_agg[:,j2] + b_agg[j2])
//   Block = 256 threads = 4 waves; block handles 64 centers.
//   Stage x tile (64x128) in LDS (pad 129 -> conflict-free column reads).
//   Wave w owns output channels [64w, 64w+64); lane = center row.
//   W_agg rows are wave-uniform -> s_load; pure v_fmac stream.
// ---------------------------------------------------------------------------
__global__ __launch_bounds__(256, 2) void agg_kernel(
    const float* __restrict__ x, const float* __restrict__ Wagg,
    const float* __restrict__ bagg, float* __restrict__ out)
{
    __shared__ float sx[64 * 129];
    const int bm0 = blockIdx.x * 64;
    const int t   = threadIdx.x;

    // stage 64 rows x 128 cols, coalesced
    #pragma unroll
    for (int q = 0; q < 32; ++q) {
        int f = q * 256 + t;
        int r = f >> 7, c = f & 127;
        sx[r * 129 + c] = x[(size_t)bm0 * 128 + f];
    }
    __syncthreads();

    const int w    = t >> 6;
    const int lane = t & 63;
    const int j0   = w * 64;

    float acc[64];
    #pragma unroll
    for (int j = 0; j < 64; ++j) acc[j] = bagg[j0 + j];        // s_load

    #pragma unroll 4
    for (int c = 0; c < 128; ++c) {
        const float xc = sx[lane * 129 + c];
        const float* Wr = Wagg + (size_t)c * OUTC + j0;         // wave-uniform
        #pragma unroll
        for (int j = 0; j < 64; ++j) acc[j] = fmaf(xc, Wr[j], acc[j]);
    }

    float* op = out + (size_t)(bm0 + lane) * OUTC + j0;
    #pragma unroll
    for (int j = 0; j < 64; j += 4) {
        float4 v = make_float4(fmaxf(acc[j+0], 0.0f), fmaxf(acc[j+1], 0.0f),
                               fmaxf(acc[j+2], 0.0f), fmaxf(acc[j+3], 0.0f));
        ((float4*)op)[j >> 2] = v;
    }
}

extern "C" void kernel_launch(void* const* d_in, const int* in_sizes, int n_in,
                              void* d_out, int out_size, void* d_ws, size_t ws_size,
                              hipStream_t stream) {
    const float* positions = (const float*)d_in[0];
    const float* features  = (const float*)d_in[1];
    const float* centers   = (const float*)d_in[2];
    const float* distances = (const float*)d_in[3];
    const float* W0        = (const float*)d_in[4];
    const float* b0        = (const float*)d_in[5];
    const float* W1        = (const float*)d_in[6];
    const float* b1        = (const float*)d_in[7];
    const float* Wagg      = (const float*)d_in[8];
    const float* bagg      = (const float*)d_in[9];
    float* out = (float*)d_out;
    float* xws = (float*)d_ws;   // B*M*128 floats = 4 MB intermediate

    op_kernel<<<BB * MM, 64, 0, stream>>>(positions, features, centers, distances,
                                          W0, b0, W1, b1, xws);
    agg_kernel<<<BB * MM / 64, 256, 0, stream>>>(xws, Wagg, bagg, out);
}

// Round 2
// 552.360 us; speedup vs baseline: 1.0660x; 1.0660x over previous
//
#include <hip/hip_runtime.h>

#define BB 4
#define NN 8192
#define MM 2048
#define CC 64
#define OPC 64
#define OUTC 256
#define K0 32
#define K1 64

// Fold-reduction step: lanes pair across XOR stride S; each lane keeps the
// half of its j-set matching its own lane bit, receives the partner's copy of
// that half, maxes. After FOLD 32..1, lane L holds cur[0] == max over all 64
// lanes of h[.][L]. Register-indexed with compile-time bounds only.
template <int S>
__device__ __forceinline__ void fold_max(float* cur, int lane) {
    const bool bit = (lane & S) != 0;
#pragma unroll
    for (int t = 0; t < S; ++t) {
        float keep = bit ? cur[t + S] : cur[t];
        float send = bit ? cur[t] : cur[t + S];
        float recv = __shfl_xor(send, S, 64);
        cur[t] = fmaxf(keep, recv);
    }
}

// ---------------------------------------------------------------------------
// Kernel 1: 4 waves/block, one center per wave.
//   Phase A: ballot-compact first K0/K1 passing indices (k smallest), early
//            exit (~4-6 chunks for uniform distances).
//   Phase B: lane = neighbor slot; W rows wave-uniform (s_load); h[64] accs
//            in VGPRs; relu+mask; register fold-max (no LDS, no barrier).
//   LDS = index lists only (~1.5 KB) -> occupancy VGPR-limited (~24 waves/CU
//   at launch_bounds(256,6)).
// ---------------------------------------------------------------------------
__global__ __launch_bounds__(256, 6) void op_kernel(
    const float* __restrict__ positions, const float* __restrict__ features,
    const float* __restrict__ centers,   const float* __restrict__ distances,
    const float* __restrict__ W0, const float* __restrict__ b0,
    const float* __restrict__ W1, const float* __restrict__ b1,
    float* __restrict__ xout)
{
    __shared__ int s_idx0[4][K0];
    __shared__ int s_idx1[4][K1];

    const int w    = threadIdx.x >> 6;
    const int lane = threadIdx.x & 63;
    const int bm   = blockIdx.x * 4 + w;
    const int b    = bm / MM;

    // ---------------- Phase A: selection (per-wave, independent) ----------
    const float* drow = distances + (size_t)bm * NN;
    int cnt0 = 0, cnt1 = 0;
    for (int base = 0; base < NN; base += 64) {
        if (cnt0 >= K0 && cnt1 >= K1) break;
        float d = drow[base + lane];
        bool p0 = (d >= 1.0f)  && (d < 2.25f);   // ring0: [1, 1.5^2)
        bool p1 = (d >= 2.25f) && (d < 9.0f);    // ring1: [1.5^2, 3^2)
        unsigned long long m0 = __ballot(p0);
        unsigned long long m1 = __ballot(p1);
        unsigned long long lt = (1ull << lane) - 1ull;
        if (cnt0 < K0) {
            int pos = cnt0 + __popcll(m0 & lt);
            if (p0 && pos < K0) s_idx0[w][pos] = base + lane;
            cnt0 += __popcll(m0);
        }
        if (cnt1 < K1) {
            int pos = cnt1 + __popcll(m1 & lt);
            if (p1 && pos < K1) s_idx1[w][pos] = base + lane;
            cnt1 += __popcll(m1);
        }
    }
    cnt0 = min(cnt0, K0);
    cnt1 = min(cnt1, K1);
    __syncthreads();   // LDS write->read visibility (also covers all 4 waves)

    const float cx = centers[(size_t)bm * 3 + 0];
    const float cy = centers[(size_t)bm * 3 + 1];
    const float cz = centers[(size_t)bm * 3 + 2];

    // ---------------- Phase B: per-ring op ---------------------------------
#pragma unroll 1   // share the unrolled body between rings (I$ + VGPRs)
    for (int ring = 0; ring < 2; ++ring) {
        const int    k    = ring ? K1 : K0;
        const int    cnt  = ring ? cnt1 : cnt0;
        const int*   sidx = ring ? s_idx1[w] : s_idx0[w];
        const float* W    = ring ? W1 : W0;
        const float* bias = ring ? b1 : b0;

        const bool valid = (lane < k) && (lane < cnt);
        const int  n     = valid ? sidx[lane & (k - 1)] : 0;

        const float* pp = positions + (size_t)((size_t)b * NN + n) * 3;
        const float rx = pp[0] - cx, ry = pp[1] - cy, rz = pp[2] - cz;

        float h[OPC];
#pragma unroll
        for (int j = 0; j < OPC; ++j) h[j] = bias[j];               // s_load
#pragma unroll
        for (int j = 0; j < OPC; ++j) h[j] = fmaf(rx, W[0*OPC + j], h[j]);
#pragma unroll
        for (int j = 0; j < OPC; ++j) h[j] = fmaf(ry, W[1*OPC + j], h[j]);
#pragma unroll
        for (int j = 0; j < OPC; ++j) h[j] = fmaf(rz, W[2*OPC + j], h[j]);

        // feature GEMV: float4 loaded just-in-time, W rows via s_load
        const float4* fp4 = (const float4*)(features + (size_t)((size_t)b * NN + n) * CC);
#pragma unroll
        for (int q = 0; q < CC / 4; ++q) {
            float4 v = fp4[q];
            const float* Wq = W + (size_t)(3 + 4 * q) * OPC;
#pragma unroll
            for (int j = 0; j < OPC; ++j) h[j] = fmaf(v.x, Wq[0*OPC + j], h[j]);
#pragma unroll
            for (int j = 0; j < OPC; ++j) h[j] = fmaf(v.y, Wq[1*OPC + j], h[j]);
#pragma unroll
            for (int j = 0; j < OPC; ++j) h[j] = fmaf(v.z, Wq[2*OPC + j], h[j]);
#pragma unroll
            for (int j = 0; j < OPC; ++j) h[j] = fmaf(v.w, Wq[3*OPC + j], h[j]);
        }

        // relu + invalid-row zeroing, then register fold-max over lanes
#pragma unroll
        for (int j = 0; j < OPC; ++j) h[j] = valid ? fmaxf(h[j], 0.0f) : 0.0f;

        fold_max<32>(h, lane);
        fold_max<16>(h, lane);
        fold_max<8>(h, lane);
        fold_max<4>(h, lane);
        fold_max<2>(h, lane);
        fold_max<1>(h, lane);
        // h[0] on lane L == f[L]

        xout[(size_t)bm * (2 * OPC) + ring * OPC + lane] = h[0];
    }
}

// ---------------------------------------------------------------------------
// Kernel 2: agg conv. Block = 256 threads; blockIdx covers (center-tile of 64)
// x (channel half of 128). Wave w owns 32 channels; lane = center row.
// x tile staged in LDS (pad 129); W_agg rows wave-uniform -> s_load.
// ---------------------------------------------------------------------------
__global__ __launch_bounds__(256, 2) void agg_kernel(
    const float* __restrict__ x, const float* __restrict__ Wagg,
    const float* __restrict__ bagg, float* __restrict__ out)
{
    __shared__ float sx[64 * 129];
    const int bm0  = (blockIdx.x >> 1) * 64;
    const int half = blockIdx.x & 1;
    const int t    = threadIdx.x;

#pragma unroll
    for (int q = 0; q < 32; ++q) {
        int f = q * 256 + t;
        int r = f >> 7, c = f & 127;
        sx[r * 129 + c] = x[(size_t)bm0 * 128 + f];
    }
    __syncthreads();

    const int w    = t >> 6;
    const int lane = t & 63;
    const int j0   = half * 128 + w * 32;

    float acc[32];
#pragma unroll
    for (int j = 0; j < 32; ++j) acc[j] = bagg[j0 + j];             // s_load

#pragma unroll 4
    for (int c = 0; c < 128; ++c) {
        const float xc = sx[lane * 129 + c];
        const float* Wr = Wagg + (size_t)c * OUTC + j0;              // s_load
#pragma unroll
        for (int j = 0; j < 32; ++j) acc[j] = fmaf(xc, Wr[j], acc[j]);
    }

    float* op = out + (size_t)(bm0 + lane) * OUTC + j0;
#pragma unroll
    for (int j = 0; j < 32; j += 4) {
        float4 v = make_float4(fmaxf(acc[j+0], 0.0f), fmaxf(acc[j+1], 0.0f),
                               fmaxf(acc[j+2], 0.0f), fmaxf(acc[j+3], 0.0f));
        ((float4*)op)[j >> 2] = v;
    }
}

extern "C" void kernel_launch(void* const* d_in, const int* in_sizes, int n_in,
                              void* d_out, int out_size, void* d_ws, size_t ws_size,
                              hipStream_t stream) {
    const float* positions = (const float*)d_in[0];
    const float* features  = (const float*)d_in[1];
    const float* centers   = (const float*)d_in[2];
    const float* distances = (const float*)d_in[3];
    const float* W0        = (const float*)d_in[4];
    const float* b0        = (const float*)d_in[5];
    const float* W1        = (const float*)d_in[6];
    const float* b1        = (const float*)d_in[7];
    const float* Wagg      = (const float*)d_in[8];
    const float* bagg      = (const float*)d_in[9];
    float* out = (float*)d_out;
    float* xws = (float*)d_ws;   // B*M*128 floats = 4 MB intermediate

    op_kernel<<<BB * MM / 4, 256, 0, stream>>>(positions, features, centers, distances,
                                               W0, b0, W1, b1, xws);
    agg_kernel<<<(BB * MM / 64) * 2, 256, 0, stream>>>(xws, Wagg, bagg, out);
}

// Round 3
// 488.214 us; speedup vs baseline: 1.2060x; 1.1314x over previous
//
#include <hip/hip_runtime.h>

#define BB 4
#define NN 8192
#define MM 2048
#define CC 64
#define OPC 64
#define OUTC 256
#define K0 32
#define K1 64

// Fold-reduction step: lanes pair across XOR stride S; each lane keeps the
// half of its j-set matching its own lane bit, receives the partner's copy of
// that half, maxes. After FOLD 32..1, lane L holds cur[0] == max over all 64
// lanes of h[.][L]. Register-indexed with compile-time bounds only.
template <int S>
__device__ __forceinline__ void fold_max(float* cur, int lane) {
    const bool bit = (lane & S) != 0;
#pragma unroll
    for (int t = 0; t < S; ++t) {
        float keep = bit ? cur[t + S] : cur[t];
        float send = bit ? cur[t] : cur[t + S];
        float recv = __shfl_xor(send, S, 64);
        cur[t] = fmaxf(keep, recv);
    }
}

// ---------------------------------------------------------------------------
// Kernel 1: 4 waves/block, one center per wave.
//   Phase A: ballot-compact first K0/K1 passing indices (k smallest), early
//            exit (~4-6 chunks for uniform distances).
//   Phase B: lane = neighbor slot; W rows wave-uniform (s_load); h[64] accs
//            in VGPRs; relu+mask; register fold-max (no LDS, no barrier).
//   launch_bounds(256,4): 128-VGPR cap. R2 lesson: (256,6) caps at 85 VGPRs
//   -> h[64] spills to scratch -> 175 MB of HBM spill traffic. h[64]+temps
//   needs ~90-110 regs; 4 waves/EU (16/CU, 50% occ) is the max spill-free.
// ---------------------------------------------------------------------------
__global__ __launch_bounds__(256, 4) void op_kernel(
    const float* __restrict__ positions, const float* __restrict__ features,
    const float* __restrict__ centers,   const float* __restrict__ distances,
    const float* __restrict__ W0, const float* __restrict__ b0,
    const float* __restrict__ W1, const float* __restrict__ b1,
    float* __restrict__ xout)
{
    __shared__ int s_idx0[4][K0];
    __shared__ int s_idx1[4][K1];

    const int w    = threadIdx.x >> 6;
    const int lane = threadIdx.x & 63;
    const int bm   = blockIdx.x * 4 + w;
    const int b    = bm / MM;

    // ---------------- Phase A: selection (per-wave, independent) ----------
    const float* drow = distances + (size_t)bm * NN;
    int cnt0 = 0, cnt1 = 0;
    for (int base = 0; base < NN; base += 64) {
        if (cnt0 >= K0 && cnt1 >= K1) break;
        float d = drow[base + lane];
        bool p0 = (d >= 1.0f)  && (d < 2.25f);   // ring0: [1, 1.5^2)
        bool p1 = (d >= 2.25f) && (d < 9.0f);    // ring1: [1.5^2, 3^2)
        unsigned long long m0 = __ballot(p0);
        unsigned long long m1 = __ballot(p1);
        unsigned long long lt = (1ull << lane) - 1ull;
        if (cnt0 < K0) {
            int pos = cnt0 + __popcll(m0 & lt);
            if (p0 && pos < K0) s_idx0[w][pos] = base + lane;
            cnt0 += __popcll(m0);
        }
        if (cnt1 < K1) {
            int pos = cnt1 + __popcll(m1 & lt);
            if (p1 && pos < K1) s_idx1[w][pos] = base + lane;
            cnt1 += __popcll(m1);
        }
    }
    cnt0 = min(cnt0, K0);
    cnt1 = min(cnt1, K1);
    __syncthreads();   // LDS write->read visibility

    const float cx = centers[(size_t)bm * 3 + 0];
    const float cy = centers[(size_t)bm * 3 + 1];
    const float cz = centers[(size_t)bm * 3 + 2];

    // ---------------- Phase B: per-ring op ---------------------------------
#pragma unroll 1   // share the unrolled body between rings (I$ + VGPRs)
    for (int ring = 0; ring < 2; ++ring) {
        const int    k    = ring ? K1 : K0;
        const int    cnt  = ring ? cnt1 : cnt0;
        const int*   sidx = ring ? s_idx1[w] : s_idx0[w];
        const float* W    = ring ? W1 : W0;
        const float* bias = ring ? b1 : b0;

        const bool valid = (lane < k) && (lane < cnt);
        const int  n     = valid ? sidx[lane & (k - 1)] : 0;

        const float* pp = positions + (size_t)((size_t)b * NN + n) * 3;
        const float rx = pp[0] - cx, ry = pp[1] - cy, rz = pp[2] - cz;

        float h[OPC];
#pragma unroll
        for (int j = 0; j < OPC; ++j) h[j] = bias[j];               // s_load
#pragma unroll
        for (int j = 0; j < OPC; ++j) h[j] = fmaf(rx, W[0*OPC + j], h[j]);
#pragma unroll
        for (int j = 0; j < OPC; ++j) h[j] = fmaf(ry, W[1*OPC + j], h[j]);
#pragma unroll
        for (int j = 0; j < OPC; ++j) h[j] = fmaf(rz, W[2*OPC + j], h[j]);

        // feature GEMV: float4 loaded just-in-time, W rows via s_load
        const float4* fp4 = (const float4*)(features + (size_t)((size_t)b * NN + n) * CC);
#pragma unroll
        for (int q = 0; q < CC / 4; ++q) {
            float4 v = fp4[q];
            const float* Wq = W + (size_t)(3 + 4 * q) * OPC;
#pragma unroll
            for (int j = 0; j < OPC; ++j) h[j] = fmaf(v.x, Wq[0*OPC + j], h[j]);
#pragma unroll
            for (int j = 0; j < OPC; ++j) h[j] = fmaf(v.y, Wq[1*OPC + j], h[j]);
#pragma unroll
            for (int j = 0; j < OPC; ++j) h[j] = fmaf(v.z, Wq[2*OPC + j], h[j]);
#pragma unroll
            for (int j = 0; j < OPC; ++j) h[j] = fmaf(v.w, Wq[3*OPC + j], h[j]);
        }

        // relu + invalid-row zeroing, then register fold-max over lanes
#pragma unroll
        for (int j = 0; j < OPC; ++j) h[j] = valid ? fmaxf(h[j], 0.0f) : 0.0f;

        fold_max<32>(h, lane);
        fold_max<16>(h, lane);
        fold_max<8>(h, lane);
        fold_max<4>(h, lane);
        fold_max<2>(h, lane);
        fold_max<1>(h, lane);
        // h[0] on lane L == f[L]

        xout[(size_t)bm * (2 * OPC) + ring * OPC + lane] = h[0];
    }
}

// ---------------------------------------------------------------------------
// Kernel 2: agg conv. Block = 256 threads; blockIdx covers (center-tile of 64)
// x (channel half of 128). Wave w owns 32 channels; lane = center row.
// x tile staged in LDS (pad 129); W_agg rows wave-uniform -> s_load.
// ---------------------------------------------------------------------------
__global__ __launch_bounds__(256, 2) void agg_kernel(
    const float* __restrict__ x, const float* __restrict__ Wagg,
    const float* __restrict__ bagg, float* __restrict__ out)
{
    __shared__ float sx[64 * 129];
    const int bm0  = (blockIdx.x >> 1) * 64;
    const int half = blockIdx.x & 1;
    const int t    = threadIdx.x;

#pragma unroll
    for (int q = 0; q < 32; ++q) {
        int f = q * 256 + t;
        int r = f >> 7, c = f & 127;
        sx[r * 129 + c] = x[(size_t)bm0 * 128 + f];
    }
    __syncthreads();

    const int w    = t >> 6;
    const int lane = t & 63;
    const int j0   = half * 128 + w * 32;

    float acc[32];
#pragma unroll
    for (int j = 0; j < 32; ++j) acc[j] = bagg[j0 + j];             // s_load

#pragma unroll 4
    for (int c = 0; c < 128; ++c) {
        const float xc = sx[lane * 129 + c];
        const float* Wr = Wagg + (size_t)c * OUTC + j0;              // s_load
#pragma unroll
        for (int j = 0; j < 32; ++j) acc[j] = fmaf(xc, Wr[j], acc[j]);
    }

    float* op = out + (size_t)(bm0 + lane) * OUTC + j0;
#pragma unroll
    for (int j = 0; j < 32; j += 4) {
        float4 v = make_float4(fmaxf(acc[j+0], 0.0f), fmaxf(acc[j+1], 0.0f),
                               fmaxf(acc[j+2], 0.0f), fmaxf(acc[j+3], 0.0f));
        ((float4*)op)[j >> 2] = v;
    }
}

extern "C" void kernel_launch(void* const* d_in, const int* in_sizes, int n_in,
                              void* d_out, int out_size, void* d_ws, size_t ws_size,
                              hipStream_t stream) {
    const float* positions = (const float*)d_in[0];
    const float* features  = (const float*)d_in[1];
    const float* centers   = (const float*)d_in[2];
    const float* distances = (const float*)d_in[3];
    const float* W0        = (const float*)d_in[4];
    const float* b0        = (const float*)d_in[5];
    const float* W1        = (const float*)d_in[6];
    const float* b1        = (const float*)d_in[7];
    const float* Wagg      = (const float*)d_in[8];
    const float* bagg      = (const float*)d_in[9];
    float* out = (float*)d_out;
    float* xws = (float*)d_ws;   // B*M*128 floats = 4 MB intermediate

    op_kernel<<<BB * MM / 4, 256, 0, stream>>>(positions, features, centers, distances,
                                               W0, b0, W1, b1, xws);
    agg_kernel<<<(BB * MM / 64) * 2, 256, 0, stream>>>(xws, Wagg, bagg, out);
}

// Round 5
// 391.751 us; speedup vs baseline: 1.5030x; 1.2462x over previous
//
#include <hip/hip_runtime.h>
#include <stdint.h>

#define BB 4
#define NN 8192
#define MM 2048
#define CC 64
#define OPC 64
#define OUTC 256
#define K0 32
#define K1 64
#define NCH 12   // K padded to 96 = 12 chunks of 8
#define CPW 4    // centers per wave: 512 blocks x 4 waves x 4 = 8192 = B*M

typedef short bf16x8 __attribute__((ext_vector_type(8)));
typedef float f32x4  __attribute__((ext_vector_type(4)));

// fp32 -> bf16 round-to-nearest-even, as raw short
__device__ __forceinline__ short f2bf(float f) {
    uint32_t u = __float_as_uint(f);
    u += 0x7FFFu + ((u >> 16) & 1u);
    return (short)(u >> 16);
}

// Stage one neighbor row into A-LDS layout [kchunk][ROWS][8] bf16.
// Column order: k0..63 = feat, k64..66 = rel xyz, k67..95 = 0.
template <int ROWS>
__device__ __forceinline__ void stage_row(short (*sA)[ROWS][8], int row,
                                          const float* __restrict__ pos,
                                          const float* __restrict__ feat,
                                          float cx, float cy, float cz) {
    const float4* fp4 = (const float4*)feat;
    float4 q[16];
#pragma unroll
    for (int t = 0; t < 16; ++t) q[t] = fp4[t];
#pragma unroll
    for (int c = 0; c < 8; ++c) {
        float4 a = q[2 * c], b = q[2 * c + 1];
        bf16x8 v;
        v[0] = f2bf(a.x); v[1] = f2bf(a.y); v[2] = f2bf(a.z); v[3] = f2bf(a.w);
        v[4] = f2bf(b.x); v[5] = f2bf(b.y); v[6] = f2bf(b.z); v[7] = f2bf(b.w);
        *(bf16x8*)&sA[c][row][0] = v;
    }
    float rx = pos[0] - cx, ry = pos[1] - cy, rz = pos[2] - cz;
    bf16x8 vr = {f2bf(rx), f2bf(ry), f2bf(rz), 0, 0, 0, 0, 0};
    *(bf16x8*)&sA[8][row][0] = vr;
    bf16x8 z = {0, 0, 0, 0, 0, 0, 0, 0};
    *(bf16x8*)&sA[9][row][0]  = z;
    *(bf16x8*)&sA[10][row][0] = z;
    *(bf16x8*)&sA[11][row][0] = z;
}

// ---------------------------------------------------------------------------
// Persistent op kernel: 512 blocks x 4 waves; wave gw handles centers
// gw*CPW .. gw*CPW+CPW-1 (R4 crash: 8 centers/wave with 512 blocks = 2x
// over-run of the 8192-center space -> OOB distance reads -> core dump).
// B-fragments (W0/W1, bf16, MFMA B-layout) live in VGPRs for the whole
// kernel. Per center: ballot-select -> LDS-stage A (bf16) -> 16x16x32 bf16
// MFMA -> masked relu/max epilogue. No __syncthreads: each wave's LDS region
// is private (same-wave lgkmcnt ordering suffices).
// LDS 73.5 KB/block -> 2 blocks/CU -> 2 waves/SIMD.
// ---------------------------------------------------------------------------
__global__ __launch_bounds__(256, 2) void op_kernel(
    const float* __restrict__ positions, const float* __restrict__ features,
    const float* __restrict__ centers,   const float* __restrict__ distances,
    const float* __restrict__ W0, const float* __restrict__ b0,
    const float* __restrict__ W1, const float* __restrict__ b1,
    float* __restrict__ xout)
{
    __shared__ __align__(16) short sA1[4][NCH][K1][8];  // 48 KB
    __shared__ __align__(16) short sA0[4][NCH][K0][8];  // 24 KB
    __shared__ int s_idx0[4][K0];
    __shared__ int s_idx1[4][K1];

    const int w    = threadIdx.x >> 6;
    const int lane = threadIdx.x & 63;
    const int quad = lane >> 4;
    const int l15  = lane & 15;
    const int gw   = blockIdx.x * 4 + w;

    // ---- one-time: B fragments for both rings (MFMA B-layout:
    //      lane holds B[k = quad*8+j][n = nt*16 + l15]) ----
    bf16x8 bfr0[3][4], bfr1[3][4];
#pragma unroll
    for (int kc = 0; kc < 3; ++kc) {
#pragma unroll
        for (int nt = 0; nt < 4; ++nt) {
            const int n = nt * 16 + l15;
            bf16x8 v0, v1;
#pragma unroll
            for (int j = 0; j < 8; ++j) {
                int k = kc * 32 + quad * 8 + j;   // permuted k
                float a0 = 0.f, a1 = 0.f;
                if (k < 64)      { a0 = W0[(3 + k) * OPC + n];  a1 = W1[(3 + k) * OPC + n]; }
                else if (k < 67) { a0 = W0[(k - 64) * OPC + n]; a1 = W1[(k - 64) * OPC + n]; }
                v0[j] = f2bf(a0); v1[j] = f2bf(a1);
            }
            bfr0[kc][nt] = v0; bfr1[kc][nt] = v1;
        }
    }
    float bias0v[4], bias1v[4];
#pragma unroll
    for (int nt = 0; nt < 4; ++nt) {
        bias0v[nt] = b0[nt * 16 + l15];
        bias1v[nt] = b1[nt * 16 + l15];
    }
    const unsigned long long lt = (1ull << lane) - 1ull;

    for (int i = 0; i < CPW; ++i) {
        const int bm = gw * CPW + i;          // < 8192 by construction
        const int b  = bm >> 11;              // MM = 2048

        // ---------------- selection: batched 8-chunk scan ------------------
        const float* drow = distances + (size_t)bm * NN;
        int cnt0 = 0, cnt1 = 0;
        for (int base = 0; base < NN; base += 512) {
            if (cnt0 >= K0 && cnt1 >= K1) break;
            float dv[8];
#pragma unroll
            for (int u = 0; u < 8; ++u) dv[u] = drow[base + u * 64 + lane];
#pragma unroll
            for (int u = 0; u < 8; ++u) {
                float d = dv[u];
                bool p0 = (d >= 1.0f)  && (d < 2.25f);
                bool p1 = (d >= 2.25f) && (d < 9.0f);
                unsigned long long m0 = __ballot(p0);
                unsigned long long m1 = __ballot(p1);
                if (cnt0 < K0) {
                    int pos = cnt0 + __popcll(m0 & lt);
                    if (p0 && pos < K0) s_idx0[w][pos] = base + u * 64 + lane;
                    cnt0 += __popcll(m0);
                }
                if (cnt1 < K1) {
                    int pos = cnt1 + __popcll(m1 & lt);
                    if (p1 && pos < K1) s_idx1[w][pos] = base + u * 64 + lane;
                    cnt1 += __popcll(m1);
                }
            }
        }
        cnt0 = min(cnt0, K0);
        cnt1 = min(cnt1, K1);

        const float cx = centers[(size_t)bm * 3 + 0];
        const float cy = centers[(size_t)bm * 3 + 1];
        const float cz = centers[(size_t)bm * 3 + 2];

        // ---------------- stage A matrices (bf16) --------------------------
        {
            int n1 = (lane < cnt1) ? s_idx1[w][lane] : 0;
            stage_row<K1>(sA1[w], lane,
                          positions + (size_t)((size_t)b * NN + n1) * 3,
                          features  + (size_t)((size_t)b * NN + n1) * CC,
                          cx, cy, cz);
        }
        if (lane < K0) {
            int n0 = (lane < cnt0) ? s_idx0[w][lane] : 0;
            stage_row<K0>(sA0[w], lane,
                          positions + (size_t)((size_t)b * NN + n0) * 3,
                          features  + (size_t)((size_t)b * NN + n0) * CC,
                          cx, cy, cz);
        }

        // ---------------- ring1 GEMM + epilogue ----------------------------
        {
            float cm[4] = {0.f, 0.f, 0.f, 0.f};
#pragma unroll
            for (int mt = 0; mt < 4; ++mt) {
                bf16x8 af[3];
#pragma unroll
                for (int kc = 0; kc < 3; ++kc)
                    af[kc] = *(bf16x8*)&sA1[w][kc * 4 + quad][mt * 16 + l15][0];
                f32x4 acc[4];
#pragma unroll
                for (int nt = 0; nt < 4; ++nt)
                    acc[nt] = (f32x4){bias1v[nt], bias1v[nt], bias1v[nt], bias1v[nt]};
#pragma unroll
                for (int kc = 0; kc < 3; ++kc)
#pragma unroll
                    for (int nt = 0; nt < 4; ++nt)
                        acc[nt] = __builtin_amdgcn_mfma_f32_16x16x32_bf16(
                            af[kc], bfr1[kc][nt], acc[nt], 0, 0, 0);
#pragma unroll
                for (int nt = 0; nt < 4; ++nt)
#pragma unroll
                    for (int r = 0; r < 4; ++r) {
                        int m = mt * 16 + quad * 4 + r;    // C/D: row=quad*4+r
                        float v = (m < cnt1) ? fmaxf(acc[nt][r], 0.f) : 0.f;
                        cm[nt] = fmaxf(cm[nt], v);
                    }
            }
#pragma unroll
            for (int nt = 0; nt < 4; ++nt) {
                cm[nt] = fmaxf(cm[nt], __shfl_xor(cm[nt], 16, 64));
                cm[nt] = fmaxf(cm[nt], __shfl_xor(cm[nt], 32, 64));
            }
            float f = (quad == 0) ? cm[0] : (quad == 1) ? cm[1]
                    : (quad == 2) ? cm[2] : cm[3];
            xout[(size_t)bm * 128 + 64 + lane] = f;   // channel = quad*16+l15 = lane
        }

        // ---------------- ring0 GEMM + epilogue ----------------------------
        {
            float cm[4] = {0.f, 0.f, 0.f, 0.f};
#pragma unroll
            for (int mt = 0; mt < 2; ++mt) {
                bf16x8 af[3];
#pragma unroll
                for (int kc = 0; kc < 3; ++kc)
                    af[kc] = *(bf16x8*)&sA0[w][kc * 4 + quad][mt * 16 + l15][0];
                f32x4 acc[4];
#pragma unroll
                for (int nt = 0; nt < 4; ++nt)
                    acc[nt] = (f32x4){bias0v[nt], bias0v[nt], bias0v[nt], bias0v[nt]};
#pragma unroll
                for (int kc = 0; kc < 3; ++kc)
#pragma unroll
                    for (int nt = 0; nt < 4; ++nt)
                        acc[nt] = __builtin_amdgcn_mfma_f32_16x16x32_bf16(
                            af[kc], bfr0[kc][nt], acc[nt], 0, 0, 0);
#pragma unroll
                for (int nt = 0; nt < 4; ++nt)
#pragma unroll
                    for (int r = 0; r < 4; ++r) {
                        int m = mt * 16 + quad * 4 + r;
                        float v = (m < cnt0) ? fmaxf(acc[nt][r], 0.f) : 0.f;
                        cm[nt] = fmaxf(cm[nt], v);
                    }
            }
#pragma unroll
            for (int nt = 0; nt < 4; ++nt) {
                cm[nt] = fmaxf(cm[nt], __shfl_xor(cm[nt], 16, 64));
                cm[nt] = fmaxf(cm[nt], __shfl_xor(cm[nt], 32, 64));
            }
            float f = (quad == 0) ? cm[0] : (quad == 1) ? cm[1]
                    : (quad == 2) ? cm[2] : cm[3];
            xout[(size_t)bm * 128 + lane] = f;
        }
    }
}

// ---------------------------------------------------------------------------
// Kernel 2: agg conv (fp32 VALU, unchanged — ~7 µs, accuracy bonus).
// ---------------------------------------------------------------------------
__global__ __launch_bounds__(256, 2) void agg_kernel(
    const float* __restrict__ x, const float* __restrict__ Wagg,
    const float* __restrict__ bagg, float* __restrict__ out)
{
    __shared__ float sx[64 * 129];
    const int bm0  = (blockIdx.x >> 1) * 64;
    const int half = blockIdx.x & 1;
    const int t    = threadIdx.x;

#pragma unroll
    for (int q = 0; q < 32; ++q) {
        int f = q * 256 + t;
        int r = f >> 7, c = f & 127;
        sx[r * 129 + c] = x[(size_t)bm0 * 128 + f];
    }
    __syncthreads();

    const int w    = t >> 6;
    const int lane = t & 63;
    const int j0   = half * 128 + w * 32;

    float acc[32];
#pragma unroll
    for (int j = 0; j < 32; ++j) acc[j] = bagg[j0 + j];

#pragma unroll 4
    for (int c = 0; c < 128; ++c) {
        const float xc = sx[lane * 129 + c];
        const float* Wr = Wagg + (size_t)c * OUTC + j0;
#pragma unroll
        for (int j = 0; j < 32; ++j) acc[j] = fmaf(xc, Wr[j], acc[j]);
    }

    float* op = out + (size_t)(bm0 + lane) * OUTC + j0;
#pragma unroll
    for (int j = 0; j < 32; j += 4) {
        float4 v = make_float4(fmaxf(acc[j+0], 0.0f), fmaxf(acc[j+1], 0.0f),
                               fmaxf(acc[j+2], 0.0f), fmaxf(acc[j+3], 0.0f));
        ((float4*)op)[j >> 2] = v;
    }
}

extern "C" void kernel_launch(void* const* d_in, const int* in_sizes, int n_in,
                              void* d_out, int out_size, void* d_ws, size_t ws_size,
                              hipStream_t stream) {
    const float* positions = (const float*)d_in[0];
    const float* features  = (const float*)d_in[1];
    const float* centers   = (const float*)d_in[2];
    const float* distances = (const float*)d_in[3];
    const float* W0        = (const float*)d_in[4];
    const float* b0        = (const float*)d_in[5];
    const float* W1        = (const float*)d_in[6];
    const float* b1        = (const float*)d_in[7];
    const float* Wagg      = (const float*)d_in[8];
    const float* bagg      = (const float*)d_in[9];
    float* out = (float*)d_out;
    float* xws = (float*)d_ws;   // B*M*128 floats = 4 MB intermediate

    // 512 blocks x 4 waves x CPW(4) centers = 8192 = B*M exactly.
    op_kernel<<<512, 256, 0, stream>>>(positions, features, centers, distances,
                                       W0, b0, W1, b1, xws);
    agg_kernel<<<(BB * MM / 64) * 2, 256, 0, stream>>>(xws, Wagg, bagg, out);
}